// Round 9
// baseline (249334.595 us; speedup 1.0000x reference)
//
#include <hip/hip_runtime.h>
#include <math.h>

// NeuralCDE on MI355X: sequential Tsit5 chain (2047*4 substeps, 6 vf evals each).
// 16 weight-stationary WGs (512 thr, 2 waves/SIMD), ALL vf weights in the
// unified VGPR/AGPR file (~176/thread). ONE tagged-packet exchange per vf eval
// over the LLC (relaxed agent-scope atomics). Round-9: throttled poll with
// exponential backoff — the unthrottled sc1 poll flood was saturating the LLC
// request path and delaying the very packet stores it waits on (round-6/8
// counters: ~1 us of spin VALU per vf = ~25-30 failed sweeps).
// All floating-point groupings bit-identical to rounds 6/8 (absmax 0.0625).

#define T_SAVE 2048
#define NCTRL 8
#define HID 128
#define WID 512
#define IN_DIM 136            // HID + NCTRL
#define NSUB 4
#define NWG 16
#define NT 512
#define RW 32                 // WID/NWG: rows per WG (L2) == cols per WG (L3)

typedef float v2f __attribute__((ext_vector_type(2)));
typedef float v4f __attribute__((ext_vector_type(4)));
typedef unsigned long long u64;

// ---- Tsit5 tableau (fp32, same literals as reference) ----
__device__ const float d_C[6] = {0.0f, 0.161f, 0.327f, 0.9f, 0.9800255409045097f, 1.0f};
__device__ const float d_AT[5][5] = {
  {0.161f, 0.f, 0.f, 0.f, 0.f},
  {-0.008480655492356989f, 0.335480655492357f, 0.f, 0.f, 0.f},
  {2.8971530571054935f, -6.359448489975075f, 4.3622954328695815f, 0.f, 0.f},
  {5.325864828439257f, -11.748883564062828f, 7.4955393428898365f, -0.09249506636175525f, 0.f},
  {5.86145544294642f, -12.92096931784711f, 8.159367898576159f, -0.071584973281401f, -0.028269050394068383f}
};
__device__ const float d_BT[6] = {0.09646076681806523f, 0.01f, 0.4798896504144996f,
                                  1.379008574103742f, -3.290069515436081f, 2.324710524099774f};

__device__ __forceinline__ float softplus_f(float x) {
  return fmaxf(x, 0.0f) + log1pf(expf(-fabsf(x)));   // == jax.nn.softplus
}

__device__ __forceinline__ void pk_fma(v2f& a, v2f x, v2f y) {
  asm("v_pk_fma_f32 %0, %1, %2, %0" : "+v"(a) : "v"(x), "v"(y));
}

// Relaxed agent-scope (LLC-coherent): the proven exchange primitive.
__device__ __forceinline__ void pkt_store(u64* p, u64 v) {
  __hip_atomic_store(p, v, __ATOMIC_RELAXED, __HIP_MEMORY_SCOPE_AGENT);
}
__device__ __forceinline__ u64 pkt_load(const u64* p) {
  return __hip_atomic_load(p, __ATOMIC_RELAXED, __HIP_MEMORY_SCOPE_AGENT);
}

// diffrax CubicInterpolation.evaluate: idx = clip(searchsorted(ts,t,'right')-1, 0, T-2)
__device__ __forceinline__ float ctrl_u(const float* __restrict__ ts,
                                        const float* __restrict__ ca, const float* __restrict__ cb,
                                        const float* __restrict__ cc, const float* __restrict__ cd,
                                        float t, int hint, int ch) {
  int idx = hint;
  while (idx + 1 <= T_SAVE - 1 && ts[idx + 1] <= t) ++idx;
  while (idx > 0 && ts[idx] > t) --idx;
  if (idx > T_SAVE - 2) idx = T_SAVE - 2;
  float x = t - ts[idx];
  int o = idx * NCTRL + ch;
  return ca[o] + x * (cb[o] + x * (cc[o] + x * cd[o]));
}

extern "C" __global__ void __launch_bounds__(NT, 2)
cde_main(const float* __restrict__ ts,
         const float* __restrict__ cd, const float* __restrict__ cc,
         const float* __restrict__ cb, const float* __restrict__ ca,
         const float* __restrict__ Wi0, const float* __restrict__ bi0,
         const float* __restrict__ Wi1, const float* __restrict__ bi1,
         const float* __restrict__ Wi2, const float* __restrict__ bi2,
         const float* __restrict__ Wf0, const float* __restrict__ bf0,
         const float* __restrict__ Wf1, const float* __restrict__ bf1,
         const float* __restrict__ Wf2, const float* __restrict__ bf2,
         const float* __restrict__ Wl,  const float* __restrict__ bl,
         float* __restrict__ out, u64* __restrict__ pkts)
{
  const int tid  = threadIdx.x;
  const int rank = blockIdx.x;

  __shared__ __align__(16) float xv[IN_DIM];
  __shared__ __align__(16) float h1s[WID];
  __shared__ __align__(16) float h2loc[RW];
  __shared__ float ysh[HID];
  __shared__ float ucI[NSUB][6][NCTRL];
  __shared__ float wls[3 * HID];
  __shared__ float bls[3];
  __shared__ int s_dead;

  const int r2  = tid >> 4;        // 0..31 local L2 row
  const int l16 = tid & 15;        // 16 lanes per L2 row
  const int e3  = tid >> 2;        // 0..127 L3 output element
  const int q4  = tid & 3;         // 4 lanes per L3 element (8-col quarters)

  if (tid == 0) s_dead = 0;
  if (tid < 3 * HID) wls[tid] = Wl[tid];
  if (tid < 3) bls[tid] = bl[tid];

  // ---- per-thread weight registers (ALL vf weights on-chip) ----
  v4f w0q[34];                     // Wf0 row tid (136 floats)
  #pragma unroll
  for (int q = 0; q < 34; ++q)
    w0q[q] = *(const v4f*)&Wf0[(size_t)tid * IN_DIM + 4 * q];
  const float b0r = bf0[tid];

  v4f w1r[8];                      // Wf1 row (rank*32+r2), cols [l16*32,+32) rotated
  #pragma unroll
  for (int k = 0; k < 8; ++k)
    w1r[k] = *(const v4f*)&Wf1[(size_t)(rank * RW + r2) * WID + l16 * 32 + ((k + l16) & 7) * 4];
  const float b1r = bf1[rank * RW + r2];

  // Wf2: element e3, this WG's 32-col slice, quarter q4 (8 cols)
  v4f w2a = *(const v4f*)&Wf2[(size_t)e3 * WID + rank * RW + q4 * 8];
  v4f w2b = *(const v4f*)&Wf2[(size_t)e3 * WID + rank * RW + q4 * 8 + 4];

  const float b2r = (tid < HID) ? bf2[tid] : 0.f;   // poller-only
  float yr = 0.f;                                    // poller-held y[i]
  float kreg[6];                                     // poller k-history (static idx)

  // ---- init MLP, fully redundant per WG ----
  if (tid < NCTRL) xv[HID + tid] = ctrl_u(ts, ca, cb, cc, cd, ts[0], 0, tid);
  __syncthreads();
  {
    float a = bi0[tid];
    #pragma unroll
    for (int e = 0; e < NCTRL; ++e) a += Wi0[tid * NCTRL + e] * xv[HID + e];
    h1s[tid] = fmaxf(a, 0.f);
  }
  __syncthreads();
  float h2v;
  {
    float a = 0.f;
    for (int e = 0; e < WID; e += 4) {
      v4f w = *(const v4f*)&Wi1[(size_t)tid * WID + e];
      v4f x = *(const v4f*)&h1s[e];
      a += w.x * x.x + w.y * x.y + w.z * x.z + w.w * x.w;
    }
    h2v = fmaxf(a + bi1[tid], 0.f);
  }
  __syncthreads();                 // everyone done reading h1 before overwrite
  h1s[tid] = h2v;                  // h1s now holds full h2 (512)
  __syncthreads();
  if (tid < HID) {
    float a = 0.f;
    for (int e = 0; e < WID; e += 4) {
      v4f w = *(const v4f*)&Wi2[(size_t)tid * WID + e];
      v4f x = *(const v4f*)&h1s[e];
      a += w.x * x.x + w.y * x.y + w.z * x.z + w.w * x.w;
    }
    float y0 = a + bi2[tid];
    ysh[tid] = y0; xv[tid] = y0; yr = y0;
  }
  __syncthreads();
  if (rank == 0 && tid < 96) {                     // out[0] = Wl @ y0 + bl
    int c = tid >> 5, l = tid & 31;
    float acc = 0.f;
    for (int e = l; e < HID; e += 32) acc += wls[c * HID + e] * ysh[e];
    #pragma unroll
    for (int o = 16; o; o >>= 1) acc += __shfl_xor(acc, o);
    if (l == 0) out[c] = acc + bls[c];
  }

  unsigned int ep = 0;

  // ---- main sequential time loop ----
  for (int iv = 0; iv < T_SAVE - 1; ++iv) {
    float t0 = ts[iv], t1 = ts[iv + 1];
    float h = (t1 - t0) * 0.25f;
    // hoist all 24 stage-time control evals; substep-0 stage-0 u directly
    if (tid < 192) {
      int j = tid / 48, st = (tid / 8) % 6, ch = tid & 7;
      float tj = t0 + (float)j * h;
      ucI[j][st][ch] = ctrl_u(ts, ca, cb, cc, cd, tj + d_C[st] * h, iv, ch);
    } else if (tid >= 384 && tid < 384 + NCTRL) {
      xv[HID + (tid - 384)] = ctrl_u(ts, ca, cb, cc, cd, t0, iv, tid - 384);
    }
    __syncthreads();
    for (int j = 0; j < NSUB; ++j) {
      #pragma unroll
      for (int s = 0; s < 6; ++s) {
        // ---- L1: h1[tid] = softplus(Wf0[tid,:] . x + b0), no reduce ----
        {
          v2f a0 = {0.f, 0.f};
          #pragma unroll
          for (int q = 0; q < 34; ++q) {
            v4f x4 = *(const v4f*)&xv[4 * q];
            pk_fma(a0, w0q[q].lo, x4.lo);
            pk_fma(a0, w0q[q].hi, x4.hi);
          }
          h1s[tid] = softplus_f(a0.x + a0.y + b0r);
        }
        __syncthreads();
        // ---- L2: 32 local rows, 16 lanes/row ----
        {
          v2f a2 = {0.f, 0.f};
          #pragma unroll
          for (int k = 0; k < 8; ++k) {
            v4f x4 = *(const v4f*)&h1s[l16 * 32 + ((k + l16) & 7) * 4];
            pk_fma(a2, w1r[k].lo, x4.lo);
            pk_fma(a2, w1r[k].hi, x4.hi);
          }
          float r = a2.x + a2.y;
          r += __shfl_xor(r, 1); r += __shfl_xor(r, 2);
          r += __shfl_xor(r, 4); r += __shfl_xor(r, 8);
          if (l16 == 0) h2loc[r2] = softplus_f(r + b1r);
        }
        __syncthreads();
        // ---- L3 quarter-dot + 4-lane shuffle reduce + packet post ----
        ++ep;
        u64* pkbase = pkts + (size_t)(ep & 1) * (NWG * HID);
        {
          v2f a3 = {0.f, 0.f};
          v2f x0 = *(const v2f*)&h2loc[8 * q4 + 0];
          v2f x1 = *(const v2f*)&h2loc[8 * q4 + 2];
          v2f x2 = *(const v2f*)&h2loc[8 * q4 + 4];
          v2f x3 = *(const v2f*)&h2loc[8 * q4 + 6];
          pk_fma(a3, w2a.lo, x0); pk_fma(a3, w2a.hi, x1);
          pk_fma(a3, w2b.lo, x2); pk_fma(a3, w2b.hi, x3);
          float v = a3.x + a3.y;
          v += __shfl_xor(v, 1);                   // (q0+q1) at even lanes
          v += __shfl_xor(v, 2);                   // (q0+q1)+(q2+q3) everywhere
          if (q4 == 0) {
            u64 pv = ((u64)ep << 32) | (u64)__float_as_uint(v);
            pkt_store(&pkbase[rank * HID + e3], pv);
          }
        }
        asm volatile("" ::: "memory");
        // ---- pollers (tid<128): backed-off poll, k + next-x build ----
        if (tid < HID) {
          const u64* pb = &pkbase[tid];
          u64 w[16];
          int guard = 0;
          for (;;) {
            #pragma unroll
            for (int m = 0; m < 16; ++m) w[m] = pkt_load(&pb[m * HID]);
            bool ok = true;
            #pragma unroll
            for (int m = 0; m < 16; ++m) ok &= ((unsigned)(w[m] >> 32) == ep);
            if (ok) break;
            if (s_dead || ++guard > 4096) { s_dead = 1; break; }
            // exponential backoff: keep the LLC request path clear so the
            // 16 WGs' packet stores can commit instead of queueing behind
            // our own poll flood.
            if (guard > 8)      __builtin_amdgcn_s_sleep(16);  // ~1024 cy
            else if (guard > 2) __builtin_amdgcn_s_sleep(4);   // ~256 cy
          }
          // bit-identical grouping to round 6's psum2 tree:
          float f[16];
          #pragma unroll
          for (int m = 0; m < 16; ++m) f[m] = __uint_as_float((unsigned)w[m]);
          float g0 = (f[0] + f[4]) + (f[8]  + f[12]);
          float g1 = (f[1] + f[5]) + (f[9]  + f[13]);
          float g2 = (f[2] + f[6]) + (f[10] + f[14]);
          float g3 = (f[3] + f[7]) + (f[11] + f[15]);
          float tot = (g0 + g1) + (g2 + g3);
          float ksv = tanhf(tot + b2r);
          kreg[s] = ksv;                           // static index (s unrolled)
          if (s < 5) {
            float inner = 0.f;
            #pragma unroll
            for (int m = 0; m < s; ++m) inner += d_AT[s][m] * kreg[m];
            inner += d_AT[s][s] * ksv;
            xv[tid] = yr + h * inner;
          } else {
            float inner = 0.f;
            #pragma unroll
            for (int m = 0; m < 5; ++m) inner += d_BT[m] * kreg[m];
            inner += d_BT[5] * ksv;
            float yn = yr + h * inner;
            yr = yn; xv[tid] = yn; ysh[tid] = yn;  // stage-0 x of next substep
          }
        } else if (tid < HID + NCTRL) {            // u-part of next stage's x
          if (s < 5)      xv[tid] = ucI[j][s + 1][tid - HID];
          else if (j < 3) xv[tid] = ucI[j + 1][0][tid - HID];
          // j==3: next interval's top writes it
        }
        __syncthreads();
      } // stages
    } // substeps
    if (rank == 0 && tid < 96) {                   // out[iv+1] = Wl @ y + bl
      int c = tid >> 5, l = tid & 31;
      float acc = 0.f;
      for (int e = l; e < HID; e += 32) acc += wls[c * HID + e] * ysh[e];
      #pragma unroll
      for (int o = 16; o; o >>= 1) acc += __shfl_xor(acc, o);
      if (l == 0) out[(iv + 1) * 3 + c] = acc + bls[c];
    }
  }
}

extern "C" void kernel_launch(void* const* d_in, const int* in_sizes, int n_in,
                              void* d_out, int out_size, void* d_ws, size_t ws_size,
                              hipStream_t stream) {
  (void)in_sizes; (void)n_in; (void)out_size; (void)ws_size;
  const float* ts  = (const float*)d_in[0];
  const float* cd  = (const float*)d_in[1];
  const float* cc  = (const float*)d_in[2];
  const float* cb  = (const float*)d_in[3];
  const float* ca  = (const float*)d_in[4];
  const float* Wi0 = (const float*)d_in[5];
  const float* bi0 = (const float*)d_in[6];
  const float* Wi1 = (const float*)d_in[7];
  const float* bi1 = (const float*)d_in[8];
  const float* Wi2 = (const float*)d_in[9];
  const float* bi2 = (const float*)d_in[10];
  const float* Wf0 = (const float*)d_in[11];
  const float* bf0 = (const float*)d_in[12];
  const float* Wf1 = (const float*)d_in[13];
  const float* bf1 = (const float*)d_in[14];
  const float* Wf2 = (const float*)d_in[15];
  const float* bf2 = (const float*)d_in[16];
  const float* Wl  = (const float*)d_in[17];
  const float* bl  = (const float*)d_in[18];
  float* out = (float*)d_out;
  u64* pkts = (u64*)d_ws;          // 2*16*128*8 = 32 KB; tags self-validate
                                   // (0xAA poison mismatches; prior-replay
                                   //  leftovers carry identical values)

  hipLaunchKernelGGL(cde_main, dim3(NWG), dim3(NT), 0, stream,
                     ts, cd, cc, cb, ca,
                     Wi0, bi0, Wi1, bi1, Wi2, bi2,
                     Wf0, bf0, Wf1, bf1, Wf2, bf2,
                     Wl, bl, out, pkts);
}

// Round 10
// 175743.713 us; speedup vs baseline: 1.4187x; 1.4187x over previous
//
#include <hip/hip_runtime.h>
#include <math.h>

// NeuralCDE on MI355X: sequential Tsit5 chain (2047*4 substeps, 6 vf evals each).
// 16 weight-stationary WGs (512 thr, 2 waves/SIMD), ALL vf weights in the
// unified VGPR/AGPR file (~176/thread). ONE exchange per vf eval over the LLC.
// Round-10: counter-barrier exchange.
//   - partials stored as plain f32, TRANSPOSED pk[elem][wg] (one 64B line per
//     element), via relaxed agent-scope stores (proven primitive)
//   - __syncthreads drains vmcnt -> all stores committed at LLC (proven r1/r2)
//   - tid0: atomicAdd(cnt,1) (RMW executes at LLC) then polls ONE line until
//     cnt >= 16*ep. Monotonic counter: no reset, no reuse hazard.
//   - readers: all 512 threads, 2x8B relaxed atomic loads each (same line per
//     element), quad shfl_xor reduce, fixed deterministic grouping.
// Ping-pong by ep&1 is safe: posting add(e+1) implies finished reading e.
// Dead-man guard: timeout latches s_dead -> fast wrong answer, never a hang.

#define T_SAVE 2048
#define NCTRL 8
#define HID 128
#define WID 512
#define IN_DIM 136            // HID + NCTRL
#define NSUB 4
#define NWG 16
#define NT 512
#define RW 32                 // WID/NWG: rows per WG (L2) == cols per WG (L3)

typedef float v2f __attribute__((ext_vector_type(2)));
typedef float v4f __attribute__((ext_vector_type(4)));
typedef unsigned long long u64;

// ---- Tsit5 tableau (fp32, same literals as reference) ----
__device__ const float d_C[6] = {0.0f, 0.161f, 0.327f, 0.9f, 0.9800255409045097f, 1.0f};
__device__ const float d_AT[5][5] = {
  {0.161f, 0.f, 0.f, 0.f, 0.f},
  {-0.008480655492356989f, 0.335480655492357f, 0.f, 0.f, 0.f},
  {2.8971530571054935f, -6.359448489975075f, 4.3622954328695815f, 0.f, 0.f},
  {5.325864828439257f, -11.748883564062828f, 7.4955393428898365f, -0.09249506636175525f, 0.f},
  {5.86145544294642f, -12.92096931784711f, 8.159367898576159f, -0.071584973281401f, -0.028269050394068383f}
};
__device__ const float d_BT[6] = {0.09646076681806523f, 0.01f, 0.4798896504144996f,
                                  1.379008574103742f, -3.290069515436081f, 2.324710524099774f};

__device__ __forceinline__ float softplus_f(float x) {
  return fmaxf(x, 0.0f) + log1pf(expf(-fabsf(x)));   // == jax.nn.softplus
}

__device__ __forceinline__ void pk_fma(v2f& a, v2f x, v2f y) {
  asm("v_pk_fma_f32 %0, %1, %2, %0" : "+v"(a) : "v"(x), "v"(y));
}

// Relaxed agent-scope (LLC-coherent): the proven exchange primitives.
__device__ __forceinline__ void st_f(float* p, float v) {
  __hip_atomic_store(p, v, __ATOMIC_RELAXED, __HIP_MEMORY_SCOPE_AGENT);
}
__device__ __forceinline__ u64 ld_u64(const u64* p) {
  return __hip_atomic_load(p, __ATOMIC_RELAXED, __HIP_MEMORY_SCOPE_AGENT);
}
__device__ __forceinline__ unsigned ld_u32(const unsigned* p) {
  return __hip_atomic_load(p, __ATOMIC_RELAXED, __HIP_MEMORY_SCOPE_AGENT);
}

// diffrax CubicInterpolation.evaluate: idx = clip(searchsorted(ts,t,'right')-1, 0, T-2)
__device__ __forceinline__ float ctrl_u(const float* __restrict__ ts,
                                        const float* __restrict__ ca, const float* __restrict__ cb,
                                        const float* __restrict__ cc, const float* __restrict__ cd,
                                        float t, int hint, int ch) {
  int idx = hint;
  while (idx + 1 <= T_SAVE - 1 && ts[idx + 1] <= t) ++idx;
  while (idx > 0 && ts[idx] > t) --idx;
  if (idx > T_SAVE - 2) idx = T_SAVE - 2;
  float x = t - ts[idx];
  int o = idx * NCTRL + ch;
  return ca[o] + x * (cb[o] + x * (cc[o] + x * cd[o]));
}

extern "C" __global__ void cde_init(unsigned* comm) {
  if (threadIdx.x < 16) comm[threadIdx.x] = 0;   // epoch counter line
}

extern "C" __global__ void __launch_bounds__(NT, 2)
cde_main(const float* __restrict__ ts,
         const float* __restrict__ cd, const float* __restrict__ cc,
         const float* __restrict__ cb, const float* __restrict__ ca,
         const float* __restrict__ Wi0, const float* __restrict__ bi0,
         const float* __restrict__ Wi1, const float* __restrict__ bi1,
         const float* __restrict__ Wi2, const float* __restrict__ bi2,
         const float* __restrict__ Wf0, const float* __restrict__ bf0,
         const float* __restrict__ Wf1, const float* __restrict__ bf1,
         const float* __restrict__ Wf2, const float* __restrict__ bf2,
         const float* __restrict__ Wl,  const float* __restrict__ bl,
         float* __restrict__ out, unsigned* __restrict__ comm)
{
  const int tid  = threadIdx.x;
  const int rank = blockIdx.x;

  unsigned* cnt = comm;                        // one line, monotonic
  float* pkbuf  = (float*)(comm + 64);         // [2][HID][NWG] = 16 KB

  __shared__ __align__(16) float xv[IN_DIM];
  __shared__ __align__(16) float h1s[WID];
  __shared__ __align__(16) float h2loc[RW];
  __shared__ float ysh[HID];
  __shared__ float ucI[NSUB][6][NCTRL];
  __shared__ float wls[3 * HID];
  __shared__ float bls[3];
  __shared__ int s_dead;

  const int r2  = tid >> 4;        // 0..31 local L2 row
  const int l16 = tid & 15;        // 16 lanes per L2 row
  const int e3  = tid >> 2;        // 0..127 L3 output element
  const int q4  = tid & 3;         // 4 lanes per L3 element (8-col quarters)

  if (tid == 0) s_dead = 0;
  if (tid < 3 * HID) wls[tid] = Wl[tid];
  if (tid < 3) bls[tid] = bl[tid];

  // ---- per-thread weight registers (ALL vf weights on-chip) ----
  v4f w0q[34];                     // Wf0 row tid (136 floats)
  #pragma unroll
  for (int q = 0; q < 34; ++q)
    w0q[q] = *(const v4f*)&Wf0[(size_t)tid * IN_DIM + 4 * q];
  const float b0r = bf0[tid];

  v4f w1r[8];                      // Wf1 row (rank*32+r2), cols [l16*32,+32) rotated
  #pragma unroll
  for (int k = 0; k < 8; ++k)
    w1r[k] = *(const v4f*)&Wf1[(size_t)(rank * RW + r2) * WID + l16 * 32 + ((k + l16) & 7) * 4];
  const float b1r = bf1[rank * RW + r2];

  // Wf2: element e3, this WG's 32-col slice, quarter q4 (8 cols)
  v4f w2a = *(const v4f*)&Wf2[(size_t)e3 * WID + rank * RW + q4 * 8];
  v4f w2b = *(const v4f*)&Wf2[(size_t)e3 * WID + rank * RW + q4 * 8 + 4];

  const float b2r = bf2[e3];       // per-quad element bias
  float yr = 0.f;                  // element state held by q4==0 lanes
  float kreg[6];                   // k-history (static idx, stage loop unrolled)

  // ---- init MLP, fully redundant per WG ----
  if (tid < NCTRL) xv[HID + tid] = ctrl_u(ts, ca, cb, cc, cd, ts[0], 0, tid);
  __syncthreads();
  {
    float a = bi0[tid];
    #pragma unroll
    for (int e = 0; e < NCTRL; ++e) a += Wi0[tid * NCTRL + e] * xv[HID + e];
    h1s[tid] = fmaxf(a, 0.f);
  }
  __syncthreads();
  float h2v;
  {
    float a = 0.f;
    for (int e = 0; e < WID; e += 4) {
      v4f w = *(const v4f*)&Wi1[(size_t)tid * WID + e];
      v4f x = *(const v4f*)&h1s[e];
      a += w.x * x.x + w.y * x.y + w.z * x.z + w.w * x.w;
    }
    h2v = fmaxf(a + bi1[tid], 0.f);
  }
  __syncthreads();                 // everyone done reading h1 before overwrite
  h1s[tid] = h2v;                  // h1s now holds full h2 (512)
  __syncthreads();
  if (tid < HID) {
    float a = 0.f;
    for (int e = 0; e < WID; e += 4) {
      v4f w = *(const v4f*)&Wi2[(size_t)tid * WID + e];
      v4f x = *(const v4f*)&h1s[e];
      a += w.x * x.x + w.y * x.y + w.z * x.z + w.w * x.w;
    }
    float y0 = a + bi2[tid];
    ysh[tid] = y0; xv[tid] = y0;
  }
  __syncthreads();
  yr = ysh[e3];                    // element state into quad lanes
  if (rank == 0 && tid < 96) {                     // out[0] = Wl @ y0 + bl
    int c = tid >> 5, l = tid & 31;
    float acc = 0.f;
    for (int e = l; e < HID; e += 32) acc += wls[c * HID + e] * ysh[e];
    #pragma unroll
    for (int o = 16; o; o >>= 1) acc += __shfl_xor(acc, o);
    if (l == 0) out[c] = acc + bls[c];
  }

  unsigned ep = 0;

  // ---- main sequential time loop ----
  for (int iv = 0; iv < T_SAVE - 1; ++iv) {
    float t0 = ts[iv], t1 = ts[iv + 1];
    float h = (t1 - t0) * 0.25f;
    // hoist all 24 stage-time control evals; substep-0 stage-0 u directly
    if (tid < 192) {
      int j = tid / 48, st = (tid / 8) % 6, ch = tid & 7;
      float tj = t0 + (float)j * h;
      ucI[j][st][ch] = ctrl_u(ts, ca, cb, cc, cd, tj + d_C[st] * h, iv, ch);
    } else if (tid >= 384 && tid < 384 + NCTRL) {
      xv[HID + (tid - 384)] = ctrl_u(ts, ca, cb, cc, cd, t0, iv, tid - 384);
    }
    __syncthreads();
    for (int j = 0; j < NSUB; ++j) {
      #pragma unroll
      for (int s = 0; s < 6; ++s) {
        // ---- L1: h1[tid] = softplus(Wf0[tid,:] . x + b0), no reduce ----
        {
          v2f a0 = {0.f, 0.f};
          #pragma unroll
          for (int q = 0; q < 34; ++q) {
            v4f x4 = *(const v4f*)&xv[4 * q];
            pk_fma(a0, w0q[q].lo, x4.lo);
            pk_fma(a0, w0q[q].hi, x4.hi);
          }
          h1s[tid] = softplus_f(a0.x + a0.y + b0r);
        }
        __syncthreads();
        // ---- L2: 32 local rows, 16 lanes/row ----
        {
          v2f a2 = {0.f, 0.f};
          #pragma unroll
          for (int k = 0; k < 8; ++k) {
            v4f x4 = *(const v4f*)&h1s[l16 * 32 + ((k + l16) & 7) * 4];
            pk_fma(a2, w1r[k].lo, x4.lo);
            pk_fma(a2, w1r[k].hi, x4.hi);
          }
          float r = a2.x + a2.y;
          r += __shfl_xor(r, 1); r += __shfl_xor(r, 2);
          r += __shfl_xor(r, 4); r += __shfl_xor(r, 8);
          if (l16 == 0) h2loc[r2] = softplus_f(r + b1r);
        }
        __syncthreads();
        // ---- L3 quarter-dot + quad reduce + transposed partial store ----
        ++ep;
        float* pk = pkbuf + (ep & 1) * (HID * NWG);
        {
          v2f a3 = {0.f, 0.f};
          v2f x0 = *(const v2f*)&h2loc[8 * q4 + 0];
          v2f x1 = *(const v2f*)&h2loc[8 * q4 + 2];
          v2f x2 = *(const v2f*)&h2loc[8 * q4 + 4];
          v2f x3 = *(const v2f*)&h2loc[8 * q4 + 6];
          pk_fma(a3, w2a.lo, x0); pk_fma(a3, w2a.hi, x1);
          pk_fma(a3, w2b.lo, x2); pk_fma(a3, w2b.hi, x3);
          float v = a3.x + a3.y;
          v += __shfl_xor(v, 1);
          v += __shfl_xor(v, 2);
          if (q4 == 0) st_f(&pk[e3 * NWG + rank], v);
        }
        __syncthreads();   // drains vmcnt per wave: partials committed at LLC
        // ---- counter barrier: 1 add + 1-line poll by tid 0 only ----
        if (tid == 0) {
          __hip_atomic_fetch_add(cnt, 1u, __ATOMIC_RELAXED, __HIP_MEMORY_SCOPE_AGENT);
          if (!s_dead) {
            unsigned target = (unsigned)NWG * ep;
            unsigned g = 0;
            while (ld_u32(cnt) < target) {
              if (++g > (1u << 15)) { s_dead = 1; break; }
            }
          }
        }
        __syncthreads();
        // ---- read 16 partials for element e3 (one 64B line), quad reduce ----
        float tot;
        {
          const u64* row = (const u64*)&pk[e3 * NWG];
          u64 d0 = ld_u64(&row[2 * q4]);
          u64 d1 = ld_u64(&row[2 * q4 + 1]);
          float f0 = __uint_as_float((unsigned)d0);
          float f1 = __uint_as_float((unsigned)(d0 >> 32));
          float f2 = __uint_as_float((unsigned)d1);
          float f3 = __uint_as_float((unsigned)(d1 >> 32));
          float p = (f0 + f1) + (f2 + f3);
          p += __shfl_xor(p, 1);
          p += __shfl_xor(p, 2);
          tot = p;                               // (p0+p1)+(p2+p3), fixed order
        }
        // ---- epilogue on q4==0 lanes: k_s, next x / y update ----
        if (q4 == 0) {
          float ksv = tanhf(tot + b2r);
          kreg[s] = ksv;                         // static index (s unrolled)
          if (s < 5) {
            float inner = 0.f;
            #pragma unroll
            for (int m = 0; m < s; ++m) inner += d_AT[s][m] * kreg[m];
            inner += d_AT[s][s] * ksv;
            xv[e3] = yr + h * inner;
          } else {
            float inner = 0.f;
            #pragma unroll
            for (int m = 0; m < 5; ++m) inner += d_BT[m] * kreg[m];
            inner += d_BT[5] * ksv;
            float yn = yr + h * inner;
            yr = yn; xv[e3] = yn; ysh[e3] = yn;  // stage-0 x of next substep
          }
        }
        if (tid >= HID && tid < HID + NCTRL) {   // u-part of next stage's x
          if (s < 5)      xv[tid] = ucI[j][s + 1][tid - HID];
          else if (j < 3) xv[tid] = ucI[j + 1][0][tid - HID];
          // j==3: next interval's top writes it
        }
        __syncthreads();
      } // stages
    } // substeps
    if (rank == 0 && tid < 96) {                 // out[iv+1] = Wl @ y + bl
      int c = tid >> 5, l = tid & 31;
      float acc = 0.f;
      for (int e = l; e < HID; e += 32) acc += wls[c * HID + e] * ysh[e];
      #pragma unroll
      for (int o = 16; o; o >>= 1) acc += __shfl_xor(acc, o);
      if (l == 0) out[(iv + 1) * 3 + c] = acc + bls[c];
    }
  }
}

extern "C" void kernel_launch(void* const* d_in, const int* in_sizes, int n_in,
                              void* d_out, int out_size, void* d_ws, size_t ws_size,
                              hipStream_t stream) {
  (void)in_sizes; (void)n_in; (void)out_size; (void)ws_size;
  const float* ts  = (const float*)d_in[0];
  const float* cd  = (const float*)d_in[1];
  const float* cc  = (const float*)d_in[2];
  const float* cb  = (const float*)d_in[3];
  const float* ca  = (const float*)d_in[4];
  const float* Wi0 = (const float*)d_in[5];
  const float* bi0 = (const float*)d_in[6];
  const float* Wi1 = (const float*)d_in[7];
  const float* bi1 = (const float*)d_in[8];
  const float* Wi2 = (const float*)d_in[9];
  const float* bi2 = (const float*)d_in[10];
  const float* Wf0 = (const float*)d_in[11];
  const float* bf0 = (const float*)d_in[12];
  const float* Wf1 = (const float*)d_in[13];
  const float* bf1 = (const float*)d_in[14];
  const float* Wf2 = (const float*)d_in[15];
  const float* bf2 = (const float*)d_in[16];
  const float* Wl  = (const float*)d_in[17];
  const float* bl  = (const float*)d_in[18];
  float* out = (float*)d_out;
  unsigned* comm = (unsigned*)d_ws;  // [0..16) counter line; +64: 16 KB pk buf
                                     // counter zeroed per launch by cde_init;
                                     // pk data self-consistent across replays
                                     // (deterministic values, counter-gated)

  hipLaunchKernelGGL(cde_init, dim3(1), dim3(64), 0, stream, comm);
  hipLaunchKernelGGL(cde_main, dim3(NWG), dim3(NT), 0, stream,
                     ts, cd, cc, cb, ca,
                     Wi0, bi0, Wi1, bi1, Wi2, bi2,
                     Wf0, bf0, Wf1, bf1, Wf2, bf2,
                     Wl, bl, out, comm);
}

// Round 11
// 145336.133 us; speedup vs baseline: 1.7156x; 1.2092x over previous
//
#include <hip/hip_runtime.h>
#include <math.h>

// NeuralCDE on MI355X: sequential Tsit5 chain (2047*4 substeps, 6 vf evals each).
// 16 weight-stationary WGs (512 thr, 2 waves/SIMD), ALL vf weights in the
// unified VGPR/AGPR file (~176/thread). ONE exchange per vf eval over the LLC.
// Round-11:
//  - tagged transposed packets: pk[elem][wg] u64 = (epoch<<32)|f32. Each
//    element's 16 packets = 2 lines; quad lane polls 4 consecutive u64s.
//    Data arrival IS the barrier: no counter RMW, no tid0 poll, no separate
//    data-read round trip. 3 barriers/stage instead of 5. No init kernel.
//  - fast HW transcendentals on the serial path: __expf/__logf softplus,
//    exp-based tanh (rel err ~2^-21; all prior reduce-order perturbations
//    left absmax at the 0.0625 bf16 floor -> ample headroom to 0.76).
// Reduction groupings preserved (f[4q+0..3] per quad lane, quad shfl tree).

#define T_SAVE 2048
#define NCTRL 8
#define HID 128
#define WID 512
#define IN_DIM 136            // HID + NCTRL
#define NSUB 4
#define NWG 16
#define NT 512
#define RW 32                 // WID/NWG: rows per WG (L2) == cols per WG (L3)

typedef float v2f __attribute__((ext_vector_type(2)));
typedef float v4f __attribute__((ext_vector_type(4)));
typedef unsigned long long u64;

// ---- Tsit5 tableau (fp32, same literals as reference) ----
__device__ const float d_C[6] = {0.0f, 0.161f, 0.327f, 0.9f, 0.9800255409045097f, 1.0f};
__device__ const float d_AT[5][5] = {
  {0.161f, 0.f, 0.f, 0.f, 0.f},
  {-0.008480655492356989f, 0.335480655492357f, 0.f, 0.f, 0.f},
  {2.8971530571054935f, -6.359448489975075f, 4.3622954328695815f, 0.f, 0.f},
  {5.325864828439257f, -11.748883564062828f, 7.4955393428898365f, -0.09249506636175525f, 0.f},
  {5.86145544294642f, -12.92096931784711f, 8.159367898576159f, -0.071584973281401f, -0.028269050394068383f}
};
__device__ const float d_BT[6] = {0.09646076681806523f, 0.01f, 0.4798896504144996f,
                                  1.379008574103742f, -3.290069515436081f, 2.324710524099774f};

// fast softplus: max(x,0) + log(1 + exp(-|x|)); arg of log in (1,2] -> accurate
__device__ __forceinline__ float softplus_f(float x) {
  return fmaxf(x, 0.0f) + __logf(1.0f + __expf(-fabsf(x)));
}
// fast tanh: e = exp(-2|x|) in (0,1]; t = (1-e)/(1+e); restore sign
__device__ __forceinline__ float tanh_f(float x) {
  float e = __expf(-2.0f * fabsf(x));
  return copysignf((1.0f - e) / (1.0f + e), x);
}

__device__ __forceinline__ void pk_fma(v2f& a, v2f x, v2f y) {
  asm("v_pk_fma_f32 %0, %1, %2, %0" : "+v"(a) : "v"(x), "v"(y));
}

// Relaxed agent-scope (LLC-coherent): the proven exchange primitives.
__device__ __forceinline__ void pkt_store(u64* p, u64 v) {
  __hip_atomic_store(p, v, __ATOMIC_RELAXED, __HIP_MEMORY_SCOPE_AGENT);
}
__device__ __forceinline__ u64 pkt_load(const u64* p) {
  return __hip_atomic_load(p, __ATOMIC_RELAXED, __HIP_MEMORY_SCOPE_AGENT);
}

// diffrax CubicInterpolation.evaluate: idx = clip(searchsorted(ts,t,'right')-1, 0, T-2)
__device__ __forceinline__ float ctrl_u(const float* __restrict__ ts,
                                        const float* __restrict__ ca, const float* __restrict__ cb,
                                        const float* __restrict__ cc, const float* __restrict__ cd,
                                        float t, int hint, int ch) {
  int idx = hint;
  while (idx + 1 <= T_SAVE - 1 && ts[idx + 1] <= t) ++idx;
  while (idx > 0 && ts[idx] > t) --idx;
  if (idx > T_SAVE - 2) idx = T_SAVE - 2;
  float x = t - ts[idx];
  int o = idx * NCTRL + ch;
  return ca[o] + x * (cb[o] + x * (cc[o] + x * cd[o]));
}

extern "C" __global__ void __launch_bounds__(NT, 2)
cde_main(const float* __restrict__ ts,
         const float* __restrict__ cd, const float* __restrict__ cc,
         const float* __restrict__ cb, const float* __restrict__ ca,
         const float* __restrict__ Wi0, const float* __restrict__ bi0,
         const float* __restrict__ Wi1, const float* __restrict__ bi1,
         const float* __restrict__ Wi2, const float* __restrict__ bi2,
         const float* __restrict__ Wf0, const float* __restrict__ bf0,
         const float* __restrict__ Wf1, const float* __restrict__ bf1,
         const float* __restrict__ Wf2, const float* __restrict__ bf2,
         const float* __restrict__ Wl,  const float* __restrict__ bl,
         float* __restrict__ out, u64* __restrict__ pkts)
{
  const int tid  = threadIdx.x;
  const int rank = blockIdx.x;

  __shared__ __align__(16) float xv[IN_DIM];
  __shared__ __align__(16) float h1s[WID];
  __shared__ __align__(16) float h2loc[RW];
  __shared__ float ysh[HID];
  __shared__ float ucI[NSUB][6][NCTRL];
  __shared__ float wls[3 * HID];
  __shared__ float bls[3];
  __shared__ int s_dead;

  const int r2  = tid >> 4;        // 0..31 local L2 row
  const int l16 = tid & 15;        // 16 lanes per L2 row
  const int e3  = tid >> 2;        // 0..127 L3 output element
  const int q4  = tid & 3;         // 4 lanes per L3 element (8-col quarters)

  if (tid == 0) s_dead = 0;
  if (tid < 3 * HID) wls[tid] = Wl[tid];
  if (tid < 3) bls[tid] = bl[tid];

  // ---- per-thread weight registers (ALL vf weights on-chip) ----
  v4f w0q[34];                     // Wf0 row tid (136 floats)
  #pragma unroll
  for (int q = 0; q < 34; ++q)
    w0q[q] = *(const v4f*)&Wf0[(size_t)tid * IN_DIM + 4 * q];
  const float b0r = bf0[tid];

  v4f w1r[8];                      // Wf1 row (rank*32+r2), cols [l16*32,+32) rotated
  #pragma unroll
  for (int k = 0; k < 8; ++k)
    w1r[k] = *(const v4f*)&Wf1[(size_t)(rank * RW + r2) * WID + l16 * 32 + ((k + l16) & 7) * 4];
  const float b1r = bf1[rank * RW + r2];

  // Wf2: element e3, this WG's 32-col slice, quarter q4 (8 cols)
  v4f w2a = *(const v4f*)&Wf2[(size_t)e3 * WID + rank * RW + q4 * 8];
  v4f w2b = *(const v4f*)&Wf2[(size_t)e3 * WID + rank * RW + q4 * 8 + 4];

  const float b2r = bf2[e3];       // per-quad element bias
  float yr = 0.f;                  // element state held by q4==0 lanes
  float kreg[6];                   // k-history (static idx, stage loop unrolled)

  // ---- init MLP, fully redundant per WG ----
  if (tid < NCTRL) xv[HID + tid] = ctrl_u(ts, ca, cb, cc, cd, ts[0], 0, tid);
  __syncthreads();
  {
    float a = bi0[tid];
    #pragma unroll
    for (int e = 0; e < NCTRL; ++e) a += Wi0[tid * NCTRL + e] * xv[HID + e];
    h1s[tid] = fmaxf(a, 0.f);
  }
  __syncthreads();
  float h2v;
  {
    float a = 0.f;
    for (int e = 0; e < WID; e += 4) {
      v4f w = *(const v4f*)&Wi1[(size_t)tid * WID + e];
      v4f x = *(const v4f*)&h1s[e];
      a += w.x * x.x + w.y * x.y + w.z * x.z + w.w * x.w;
    }
    h2v = fmaxf(a + bi1[tid], 0.f);
  }
  __syncthreads();                 // everyone done reading h1 before overwrite
  h1s[tid] = h2v;                  // h1s now holds full h2 (512)
  __syncthreads();
  if (tid < HID) {
    float a = 0.f;
    for (int e = 0; e < WID; e += 4) {
      v4f w = *(const v4f*)&Wi2[(size_t)tid * WID + e];
      v4f x = *(const v4f*)&h1s[e];
      a += w.x * x.x + w.y * x.y + w.z * x.z + w.w * x.w;
    }
    float y0 = a + bi2[tid];
    ysh[tid] = y0; xv[tid] = y0;
  }
  __syncthreads();
  yr = ysh[e3];                    // element state into quad lanes
  if (rank == 0 && tid < 96) {                     // out[0] = Wl @ y0 + bl
    int c = tid >> 5, l = tid & 31;
    float acc = 0.f;
    for (int e = l; e < HID; e += 32) acc += wls[c * HID + e] * ysh[e];
    #pragma unroll
    for (int o = 16; o; o >>= 1) acc += __shfl_xor(acc, o);
    if (l == 0) out[c] = acc + bls[c];
  }

  unsigned ep = 0;

  // ---- main sequential time loop ----
  for (int iv = 0; iv < T_SAVE - 1; ++iv) {
    float t0 = ts[iv], t1 = ts[iv + 1];
    float h = (t1 - t0) * 0.25f;
    // hoist all 24 stage-time control evals; substep-0 stage-0 u directly
    if (tid < 192) {
      int j = tid / 48, st = (tid / 8) % 6, ch = tid & 7;
      float tj = t0 + (float)j * h;
      ucI[j][st][ch] = ctrl_u(ts, ca, cb, cc, cd, tj + d_C[st] * h, iv, ch);
    } else if (tid >= 384 && tid < 384 + NCTRL) {
      xv[HID + (tid - 384)] = ctrl_u(ts, ca, cb, cc, cd, t0, iv, tid - 384);
    }
    __syncthreads();
    for (int j = 0; j < NSUB; ++j) {
      #pragma unroll
      for (int s = 0; s < 6; ++s) {
        // ---- L1: h1[tid] = softplus(Wf0[tid,:] . x + b0), no reduce ----
        {
          v2f a0 = {0.f, 0.f};
          #pragma unroll
          for (int q = 0; q < 34; ++q) {
            v4f x4 = *(const v4f*)&xv[4 * q];
            pk_fma(a0, w0q[q].lo, x4.lo);
            pk_fma(a0, w0q[q].hi, x4.hi);
          }
          h1s[tid] = softplus_f(a0.x + a0.y + b0r);
        }
        __syncthreads();
        // ---- L2: 32 local rows, 16 lanes/row ----
        {
          v2f a2 = {0.f, 0.f};
          #pragma unroll
          for (int k = 0; k < 8; ++k) {
            v4f x4 = *(const v4f*)&h1s[l16 * 32 + ((k + l16) & 7) * 4];
            pk_fma(a2, w1r[k].lo, x4.lo);
            pk_fma(a2, w1r[k].hi, x4.hi);
          }
          float r = a2.x + a2.y;
          r += __shfl_xor(r, 1); r += __shfl_xor(r, 2);
          r += __shfl_xor(r, 4); r += __shfl_xor(r, 8);
          if (l16 == 0) h2loc[r2] = softplus_f(r + b1r);
        }
        __syncthreads();
        // ---- L3 quarter-dot + quad reduce + tagged transposed packet post ----
        ++ep;
        u64* pk = pkts + (size_t)(ep & 1) * (HID * NWG);
        {
          v2f a3 = {0.f, 0.f};
          v2f x0 = *(const v2f*)&h2loc[8 * q4 + 0];
          v2f x1 = *(const v2f*)&h2loc[8 * q4 + 2];
          v2f x2 = *(const v2f*)&h2loc[8 * q4 + 4];
          v2f x3 = *(const v2f*)&h2loc[8 * q4 + 6];
          pk_fma(a3, w2a.lo, x0); pk_fma(a3, w2a.hi, x1);
          pk_fma(a3, w2b.lo, x2); pk_fma(a3, w2b.hi, x3);
          float v = a3.x + a3.y;
          v += __shfl_xor(v, 1);
          v += __shfl_xor(v, 2);
          if (q4 == 0) {
            u64 pv = ((u64)ep << 32) | (u64)__float_as_uint(v);
            pkt_store(&pk[e3 * NWG + rank], pv);   // pk[elem][wg]
          }
        }
        asm volatile("" ::: "memory");             // keep post before poll
        // ---- poll own element's 4 packets (within one 64B line) ----
        float tot;
        {
          const u64* pb = &pk[e3 * NWG + 4 * q4];
          u64 w0, w1, w2, w3;
          int guard = 0;
          for (;;) {
            w0 = pkt_load(pb + 0);
            w1 = pkt_load(pb + 1);
            w2 = pkt_load(pb + 2);
            w3 = pkt_load(pb + 3);
            if (((unsigned)(w0 >> 32) == ep) & ((unsigned)(w1 >> 32) == ep) &
                ((unsigned)(w2 >> 32) == ep) & ((unsigned)(w3 >> 32) == ep)) break;
            if (s_dead || ++guard > (1 << 16)) { s_dead = 1; break; }
          }
          float f0 = __uint_as_float((unsigned)w0);
          float f1 = __uint_as_float((unsigned)w1);
          float f2 = __uint_as_float((unsigned)w2);
          float f3 = __uint_as_float((unsigned)w3);
          float p = (f0 + f1) + (f2 + f3);         // wgs 4q4..4q4+3, fixed order
          p += __shfl_xor(p, 1);
          p += __shfl_xor(p, 2);
          tot = p;                                 // (g0+g1)+(g2+g3)
        }
        // ---- epilogue on q4==0 lanes: k_s, next x / y update ----
        if (q4 == 0) {
          float ksv = tanh_f(tot + b2r);
          kreg[s] = ksv;                           // static index (s unrolled)
          if (s < 5) {
            float inner = 0.f;
            #pragma unroll
            for (int m = 0; m < s; ++m) inner += d_AT[s][m] * kreg[m];
            inner += d_AT[s][s] * ksv;
            xv[e3] = yr + h * inner;
          } else {
            float inner = 0.f;
            #pragma unroll
            for (int m = 0; m < 5; ++m) inner += d_BT[m] * kreg[m];
            inner += d_BT[5] * ksv;
            float yn = yr + h * inner;
            yr = yn; xv[e3] = yn; ysh[e3] = yn;    // stage-0 x of next substep
          }
        }
        if (tid >= HID && tid < HID + NCTRL) {     // u-part of next stage's x
          if (s < 5)      xv[tid] = ucI[j][s + 1][tid - HID];
          else if (j < 3) xv[tid] = ucI[j + 1][0][tid - HID];
          // j==3: next interval's top writes it
        }
        __syncthreads();
      } // stages
    } // substeps
    if (rank == 0 && tid < 96) {                   // out[iv+1] = Wl @ y + bl
      int c = tid >> 5, l = tid & 31;
      float acc = 0.f;
      for (int e = l; e < HID; e += 32) acc += wls[c * HID + e] * ysh[e];
      #pragma unroll
      for (int o = 16; o; o >>= 1) acc += __shfl_xor(acc, o);
      if (l == 0) out[(iv + 1) * 3 + c] = acc + bls[c];
    }
  }
}

extern "C" void kernel_launch(void* const* d_in, const int* in_sizes, int n_in,
                              void* d_out, int out_size, void* d_ws, size_t ws_size,
                              hipStream_t stream) {
  (void)in_sizes; (void)n_in; (void)out_size; (void)ws_size;
  const float* ts  = (const float*)d_in[0];
  const float* cd  = (const float*)d_in[1];
  const float* cc  = (const float*)d_in[2];
  const float* cb  = (const float*)d_in[3];
  const float* ca  = (const float*)d_in[4];
  const float* Wi0 = (const float*)d_in[5];
  const float* bi0 = (const float*)d_in[6];
  const float* Wi1 = (const float*)d_in[7];
  const float* bi1 = (const float*)d_in[8];
  const float* Wi2 = (const float*)d_in[9];
  const float* bi2 = (const float*)d_in[10];
  const float* Wf0 = (const float*)d_in[11];
  const float* bf0 = (const float*)d_in[12];
  const float* Wf1 = (const float*)d_in[13];
  const float* bf1 = (const float*)d_in[14];
  const float* Wf2 = (const float*)d_in[15];
  const float* bf2 = (const float*)d_in[16];
  const float* Wl  = (const float*)d_in[17];
  const float* bl  = (const float*)d_in[18];
  float* out = (float*)d_out;
  u64* pkts = (u64*)d_ws;          // 2*128*16*8 = 32 KB. Tags self-validate:
                                   // 0xAA poison (tag 0xAAAAAAAA) never matches
                                   // ep <= ~3e5; prior-replay tags only match at
                                   // identical epochs carrying bit-identical
                                   // deterministic values. No init kernel.

  hipLaunchKernelGGL(cde_main, dim3(NWG), dim3(NT), 0, stream,
                     ts, cd, cc, cb, ca,
                     Wi0, bi0, Wi1, bi1, Wi2, bi2,
                     Wf0, bf0, Wf1, bf1, Wf2, bf2,
                     Wl, bl, out, pkts);
}